// Round 1
// 250.225 us; speedup vs baseline: 1.0648x; 1.0648x over previous
//
#include <hip/hip_runtime.h>

#define NPRI 21504
#define BATCH 64
#define KTOP 1024
#define NCH 21
#define SUPW 8704   // packed upper-triangle words/image = 64 * sum(16-g) = 64*136

typedef unsigned long long u64;
typedef unsigned int u32;

// correctly-rounded f32 exp via f64 libm exp (validated: absmax 3e-8)
__device__ __forceinline__ float crexpf(float x) { return (float)exp((double)x); }

__device__ __forceinline__ u64 readlane64(u64 v, int lane) {
  int lo = __builtin_amdgcn_readlane((int)(u32)v, lane);
  int hi = __builtin_amdgcn_readlane((int)(u32)(v >> 32), lane);
  return ((u64)(u32)hi << 32) | (u64)(u32)lo;
}

// packed row base for group g: 64 * (16g - g(g-1)/2)
__device__ __forceinline__ int supBase(int g) {
  return 64 * (16 * g - (g * (g - 1)) / 2);
}

// Key packing (validated): key = (score_bits<<15) | (NPRI-1-idx). Unique keys;
// desc u64 order == (score desc, idx asc) == lax.top_k stable order => any
// correct top-1024 structure is bit-exact.

// K1: fused score + per-chunk bitonic sort (r12-validated, 1344 blocks, 8 KB).
__global__ __launch_bounds__(256) void k_sort(const float* __restrict__ confs,
                                              u64* __restrict__ keyG) {
  const int b = blockIdx.x / NCH;
  const int c = blockIdx.x % NCH;
  __shared__ u64 ks[KTOP];
  const float2* cf = (const float2*)confs + (size_t)b * NPRI + c * KTOP;
  for (int i = threadIdx.x; i < KTOP; i += 256) {
    float2 v = cf[i];
    float m = fmaxf(v.x, v.y);
    float e0 = crexpf(v.x - m);
    float e1 = crexpf(v.y - m);
    float s = e1 / (e0 + e1);          // exact f32 steps (validated)
    int idx = c * KTOP + i;
    ks[i] = ((u64)__float_as_uint(s) << 15) | (u64)(NPRI - 1 - idx);
  }
  for (int k = 2; k <= KTOP; k <<= 1) {
    for (int j = k >> 1; j > 0; j >>= 1) {
      __syncthreads();
      for (int l = threadIdx.x; l < KTOP; l += 256) {
        int p = l ^ j;
        if (p > l) {
          u64 a = ks[l], q = ks[p];
          bool up = ((l & k) == 0);
          if ((a > q) != up) { ks[l] = q; ks[p] = a; }
        }
      }
    }
  }
  __syncthreads();
  u64* dst = keyG + (size_t)b * NPRI + (size_t)c * KTOP;
  for (int i = threadIdx.x; i < KTOP; i += 256) dst[i] = ks[i];
}

// K2: 3 blocks/image: serially merge 7 runs -> top-1024 (r17-validated).
__global__ __launch_bounds__(256) void k_merge7(const u64* __restrict__ keyG,
                                                u64* __restrict__ midG) {
  const int b = blockIdx.x / 3;
  const int p3 = blockIdx.x % 3;
  __shared__ u64 A[KTOP];
  __shared__ u64 Bv[KTOP];
  const u64* src = keyG + ((size_t)b * NCH + p3 * 7) * KTOP;
  for (int i = threadIdx.x; i < KTOP; i += 256) A[i] = src[i];
  for (int c = 1; c < 7; c++) {
    __syncthreads();
    for (int i = threadIdx.x; i < KTOP; i += 256)
      Bv[i] = src[(size_t)c * KTOP + (KTOP - 1 - i)];   // reversed: asc
    __syncthreads();
    for (int i = threadIdx.x; i < KTOP; i += 256)
      if (Bv[i] > A[i]) A[i] = Bv[i];                    // half-cleaner
    for (int j = KTOP / 2; j > 0; j >>= 1) {             // clean -> desc
      __syncthreads();
      for (int l = threadIdx.x; l < KTOP; l += 256) {
        int p = l ^ j;
        if (p > l) {
          u64 a = A[l], q = A[p];
          if (a < q) { A[l] = q; A[p] = a; }
        }
      }
    }
  }
  __syncthreads();
  u64* d = midG + ((size_t)b * 3 + p3) * KTOP;
  for (int i = threadIdx.x; i < KTOP; i += 256) d[i] = A[i];
}

// K3: per image: merge 3 mids -> top-1024, then validated decode + valid-ballot.
__global__ __launch_bounds__(256) void k_merge3(const u64* __restrict__ midG,
                                                const float* __restrict__ locs,
                                                const float* __restrict__ priors,
                                                float* __restrict__ boxF,
                                                float* __restrict__ scoreF,
                                                u64* __restrict__ validW) {
  const int b = blockIdx.x;
  const int t = threadIdx.x;
  __shared__ u64 A[KTOP];
  __shared__ u64 Bv[KTOP];
  const u64* src = midG + (size_t)b * 3 * KTOP;
  for (int i = t; i < KTOP; i += 256) A[i] = src[i];
  for (int c = 1; c < 3; c++) {
    __syncthreads();
    for (int i = t; i < KTOP; i += 256)
      Bv[i] = src[(size_t)c * KTOP + (KTOP - 1 - i)];
    __syncthreads();
    for (int i = t; i < KTOP; i += 256)
      if (Bv[i] > A[i]) A[i] = Bv[i];
    for (int j = KTOP / 2; j > 0; j >>= 1) {
      __syncthreads();
      for (int l = t; l < KTOP; l += 256) {
        int p = l ^ j;
        if (p > l) {
          u64 a = A[l], q = A[p];
          if (a < q) { A[l] = q; A[p] = a; }
        }
      }
    }
  }
  __syncthreads();
  // decode top-1024: f32-stepwise (identical expressions to validated round 7)
  for (int i = t; i < KTOP; i += 256) {
    u64 K = A[i];
    float sv = __uint_as_float((u32)(K >> 15));
    int idx = NPRI - 1 - (int)(K & 0x7FFFu);
    float4 lo = ((const float4*)locs)[(size_t)b * NPRI + idx];
    float4 pr = ((const float4*)priors)[idx];
    float cx = pr.x + (lo.x * 0.1f) * pr.z;
    float cy = pr.y + (lo.y * 0.1f) * pr.w;
    float w  = pr.z * crexpf(lo.z * 0.2f);
    float h  = pr.w * crexpf(lo.w * 0.2f);
    float x1 = cx - w * 0.5f;
    float y1 = cy - h * 0.5f;
    float x2 = x1 + w;
    float y2 = y1 + h;
    size_t o = (size_t)b * KTOP + i;
    boxF[o * 4 + 0] = x1;
    boxF[o * 4 + 1] = y1;
    boxF[o * 4 + 2] = x2;
    boxF[o * 4 + 3] = y2;
    scoreF[o] = sv;
    u64 mask = __ballot(sv > 0.5f);       // wave covers group i>>6
    if ((t & 63) == 0) validW[(size_t)b * 16 + (i >> 6)] = mask;
  }
}

// K4: upper-triangle suppression bitmask (r13/r17-validated IoU bits), packed
// rows + XCD-affinity grid (unchanged).
__global__ __launch_bounds__(256) void k_iou(const float* __restrict__ boxF,
                                             u64* __restrict__ supP) {
  const int bid = blockIdx.x;
  const int x8 = bid & 7;
  const int q = bid >> 3;
  const int bslot = q / 40;
  int task = q - bslot * 40;           // 0..39
  const int b = bslot * 8 + x8;        // image
  int g = 0, base = 0;
  for (int gg = 0; gg < 16; gg++) {
    int cg = (16 - gg + 3) >> 2;
    if (task < base + cg) { g = gg; break; }
    base += cg;
  }
  const int c = task - base;
  const int w0 = g + 4 * c;            // first word of this chunk
  __shared__ float4 BXS[256];
  __shared__ float ARS[256];
  const float4* bb = (const float4*)(boxF + (size_t)b * KTOP * 4);
  {
    int j = w0 * 64 + threadIdx.x;
    if (j < KTOP) {
      float4 v = bb[j];
      BXS[threadIdx.x] = v;
      ARS[threadIdx.x] = fmaxf(v.z - v.x, 0.0f) * fmaxf(v.w - v.y, 0.0f);
    }
  }
  const int r = threadIdx.x & 63;
  const int v = threadIdx.x >> 6;      // wave 0..3
  const int i = g * 64 + r;
  float4 bi = bb[i];
  float a = fmaxf(bi.z - bi.x, 0.0f) * fmaxf(bi.w - bi.y, 0.0f);
  __syncthreads();
  const int w = w0 + v;
  if (w < 16) {
    u64 word = 0;
    const int lbase = v * 64;
    for (int jb = 0; jb < 64; jb++) {
      int lj = lbase + jb;
      float4 bj = BXS[lj];             // broadcast (w uniform in wave)
      float aj = ARS[lj];
      float lx = fmaxf(bi.x, bj.x);
      float ly = fmaxf(bi.y, bj.y);
      float rx = fminf(bi.z, bj.z);
      float ry = fminf(bi.w, bj.w);
      float iw = fmaxf(rx - lx, 0.0f);
      float ih = fmaxf(ry - ly, 0.0f);
      float inter = iw * ih;
      float uni = (a + aj) - inter;
      float iou = inter / fmaxf(uni, 1e-9f);
      if (iou > 0.4f) word |= (1ULL << jb);
    }
    if (w == g) word &= (r == 63) ? 0ULL : (~0ULL << (r + 1));   // j > i
    supP[(size_t)b * SUPW + supBase(g) + (size_t)r * (16 - g) + (w - g)] = word;
  }
}

// K5: greedy scan v7 — frontier-fixpoint NMS. Greedy NMS == iterate:
//   sup      = OR of rows of alive boxes          (boxes with an alive
//                                                  predecessor-suppressor)
//   frontier = alive & ~sup                        -> definitely kept
//   alive    = alive & ~frontier & ~(OR rows of frontier)
// until alive empty. Round count = longest suppression chain (~2-3 here)
// instead of ~1024 serial readlane steps. Both sweeps are fully parallel:
// thread (w = t>>4, k = t&15) OR-accumulates word w over rows i = k mod 16,
// then a 4-step shfl_xor reduce. Ping-pong alive buffers + parity-indexed
// continuation flag keep it to 2 race-free barriers per round. Bits identical
// to the r12-validated chain (same packed rows, same j>i masking).
__global__ __launch_bounds__(256) void k_scan(const u64* __restrict__ supP,
                                              const u64* __restrict__ validW,
                                              const float* __restrict__ boxF,
                                              const float* __restrict__ scoreF,
                                              float* __restrict__ out) {
  extern __shared__ u64 rows[];        // SUPW u64 = 69632 B
  const int b = blockIdx.x;
  const int t = threadIdx.x;
  const int lane = t & 63;
  const int wv = t >> 6;               // wave 0..3
  __shared__ u64 aliveA[16], aliveB[16], supW[16], keepW[16];
  __shared__ int contF[2];
  const u64* supB = supP + (size_t)b * SUPW;
  // async bulk stage: 68 chunks x 1 KB (unchanged, r17-validated)
  {
    const unsigned char* gb = (const unsigned char*)supB;
    unsigned char* lb = (unsigned char*)rows;
    for (int c = wv; c < 68; c += 4) {
      int off = c << 10;
      __builtin_amdgcn_global_load_lds(
          (const __attribute__((address_space(1))) unsigned int*)(gb + off + lane * 16),
          (__attribute__((address_space(3))) unsigned int*)(lb + off),
          16, 0, 0);
    }
  }
  if (t < 16) { aliveA[t] = validW[(size_t)b * 16 + t]; keepW[t] = 0; }
  if (t == 0) contF[0] = 0;
  __syncthreads();                     // drains vmcnt; init visible

  u64* cur = aliveA;
  u64* nxt = aliveB;
  const int w = t >> 4;                // owned suppression word 0..15
  const int k = t & 15;                // lane within word-team
  for (int round = 0;; ++round) {
    const int p = round & 1;
    // region 1: supW[w] = OR over alive rows i (g(i) <= w) of their word w
    u64 acc = 0;
    for (int g = 0; g <= w; ++g) {
      int base = supBase(g) + (w - g);
      int rl = 16 - g;
      u64 am = cur[g];
      for (int r = k; r < 64; r += 16)
        if ((am >> r) & 1) acc |= rows[base + r * rl];
    }
    acc |= __shfl_xor(acc, 1);
    acc |= __shfl_xor(acc, 2);
    acc |= __shfl_xor(acc, 4);
    acc |= __shfl_xor(acc, 8);
    if (k == 0) supW[w] = acc;
    __syncthreads();                   // A: supW stable
    // region 2: removed-by-frontier sweep + state update (writes go to nxt)
    u64 acc2 = 0;
    for (int g = 0; g <= w; ++g) {
      int base = supBase(g) + (w - g);
      int rl = 16 - g;
      u64 fm = cur[g] & ~supW[g];      // frontier bits of group g
      for (int r = k; r < 64; r += 16)
        if ((fm >> r) & 1) acc2 |= rows[base + r * rl];
    }
    acc2 |= __shfl_xor(acc2, 1);
    acc2 |= __shfl_xor(acc2, 2);
    acc2 |= __shfl_xor(acc2, 4);
    acc2 |= __shfl_xor(acc2, 8);
    if (k == 0) {
      u64 a = cur[w];
      u64 f = a & ~supW[w];
      keepW[w] |= f;
      u64 na = a & ~(f | acc2);
      nxt[w] = na;
      if (na) contF[p] = 1;            // benign same-value race
    }
    if (t == 0) contF[p ^ 1] = 0;      // pre-zero next round's flag
    __syncthreads();                   // B: keepW/nxt/contF stable
    if (!contF[p]) break;              // uniform: all threads read same value
    u64* tmp = cur; cur = nxt; nxt = tmp;
  }
  const float* bb = boxF + (size_t)b * KTOP * 4;
  const float* sc = scoreF + (size_t)b * KTOP;
  const float4* bb4 = (const float4*)bb;
  for (int i = t; i < KTOP; i += 256) {
    float kf = ((keepW[i >> 6] >> (i & 63)) & 1ULL) ? 1.0f : 0.0f;
    float4 bv = bb4[i];
    size_t o5 = ((size_t)b * KTOP + i) * 5;
    out[o5 + 0] = bv.x * kf;
    out[o5 + 1] = bv.y * kf;
    out[o5 + 2] = bv.z * kf;
    out[o5 + 3] = bv.w * kf;
    out[o5 + 4] = sc[i] * kf;
    out[(size_t)BATCH * KTOP * 5 + (size_t)b * KTOP + i] = kf;
  }
}

extern "C" void kernel_launch(void* const* d_in, const int* in_sizes, int n_in,
                              void* d_out, int out_size, void* d_ws, size_t ws_size,
                              hipStream_t stream) {
  const float* locs = nullptr;
  const float* confs = nullptr;
  const float* priors = nullptr;
  for (int i = 0; i < n_in; i++) {
    if (in_sizes[i] == BATCH * NPRI * 4) locs = (const float*)d_in[i];
    else if (in_sizes[i] == BATCH * NPRI * 2) confs = (const float*)d_in[i];
    else if (in_sizes[i] == NPRI * 4) priors = (const float*)d_in[i];
  }
  float* out = (float*)d_out;   // f32: [B,K,5] dets ++ [B,K] keep

  char* ws = (char*)d_ws;
  size_t off = 0;
  u64* keyG = (u64*)(ws + off);          // B*21*1024*8 = 11,010,048
  u64* supP = (u64*)(ws + off);          // alias: keyG dead after k_merge7 (4,456,448)
  off += (size_t)BATCH * NCH * KTOP * 8;
  u64* midG = (u64*)(ws + off);          off += (size_t)BATCH * 3 * KTOP * 8;   // 1,572,864
  float* boxF = (float*)(ws + off);      off += (size_t)BATCH * KTOP * 4 * 4;   // 1,048,576
  float* scoreF = (float*)(ws + off);    off += (size_t)BATCH * KTOP * 4;       //   262,144
  u64* validW = (u64*)(ws + off);        off += (size_t)BATCH * 16 * 8;         //     8,192
  // total ~13.9 MB

  k_sort<<<BATCH * NCH, 256, 0, stream>>>(confs, keyG);
  k_merge7<<<BATCH * 3, 256, 0, stream>>>(keyG, midG);
  k_merge3<<<BATCH, 256, 0, stream>>>(midG, locs, priors, boxF, scoreF, validW);
  k_iou<<<2560, 256, 0, stream>>>(boxF, supP);
  k_scan<<<BATCH, 256, SUPW * 8, stream>>>(supP, validW, boxF, scoreF, out);
}

// Round 2
// 183.303 us; speedup vs baseline: 1.4536x; 1.3651x over previous
//
#include <hip/hip_runtime.h>

#define NPRI 21504
#define BATCH 64
#define KTOP 1024
#define NCH 21
#define SUPW 8704   // packed upper-triangle words/image = 64 * sum(16-g) = 64*136

typedef unsigned long long u64;
typedef unsigned int u32;

// correctly-rounded f32 exp via f64 libm exp (validated: absmax 3e-8)
__device__ __forceinline__ float crexpf(float x) { return (float)exp((double)x); }

__device__ __forceinline__ u64 readlane64(u64 v, int lane) {
  int lo = __builtin_amdgcn_readlane((int)(u32)v, lane);
  int hi = __builtin_amdgcn_readlane((int)(u32)(v >> 32), lane);
  return ((u64)(u32)hi << 32) | (u64)(u32)lo;
}

// packed row base for group g: 64 * (16g - g(g-1)/2)
__device__ __forceinline__ int supBase(int g) {
  return 64 * (16 * g - (g * (g - 1)) / 2);
}

// Key packing (validated): key = (score_bits<<15) | (NPRI-1-idx). Unique keys;
// desc u64 order == (score desc, idx asc) == lax.top_k stable order => any
// correct top-1024 structure is bit-exact.
__device__ __forceinline__ u64 mkkey(float x, float y, int idx) {
  float m = fmaxf(x, y);
  float e0 = crexpf(x - m);
  float e1 = crexpf(y - m);
  float s = e1 / (e0 + e1);          // exact f32 steps (validated)
  return ((u64)__float_as_uint(s) << 15) | (u64)(NPRI - 1 - idx);
}

// ---- register/shuffle bitonic primitives -----------------------------------
// Item index i = w*256 + l*4 + s  (wave bits 9:8, lane bits 7:2, slot bits 1:0).
// Comparator (k,j) on pair (lo, hi=lo^j): if ((lo&k)==0) lo<-max (descending
// pair) else lo<-min. Same network as the r12-validated LDS bitonic; keys are
// unique so the sorted result is bit-identical.

__device__ __forceinline__ u64 shflx64(u64 v, int m) {
  int lo = __shfl_xor((int)(u32)v, m, 64);
  int hi = __shfl_xor((int)(u32)(v >> 32), m, 64);
  return ((u64)(u32)hi << 32) | (u64)(u32)lo;
}

__device__ __forceinline__ void cex2(u64& lo, u64& hi, bool up) {
  u64 a = lo, b = hi;
  bool g = a > b;
  u64 mx = g ? a : b, mn = g ? b : a;
  lo = up ? mx : mn;
  hi = up ? mn : mx;
}

__device__ __forceinline__ void cexs(u64& v, int m, bool keep_max) {
  u64 pv = shflx64(v, m);
  v = ((v > pv) == keep_max) ? v : pv;
}

// stages j = jmax..1 (jmax<=128) of a bitonic merge, direction `up` uniform
// across the thread's 4 slots (holds for all k>=4 call sites).
__device__ __forceinline__ void bm_low(u64& v0, u64& v1, u64& v2, u64& v3,
                                       int l, bool up, int jmax) {
  for (int m = jmax >> 2; m >= 1; m >>= 1) {   // j = 4*m (lane-xor stages)
    bool km = (up == ((l & m) == 0));
    cexs(v0, m, km); cexs(v1, m, km); cexs(v2, m, km); cexs(v3, m, km);
  }
  cex2(v0, v2, up); cex2(v1, v3, up);          // j = 2
  cex2(v0, v1, up); cex2(v2, v3, up);          // j = 1
}

// one cross-wave LDS exchange stage: j = 256*wm, direction `up` per-thread
// (uniform within a wave). Layout lane-low: addr = w*256 + s*64 + l.
__device__ __forceinline__ void bm_lds(u64* ks, u64& v0, u64& v1, u64& v2, u64& v3,
                                       int l, int w, int wm, bool up) {
  ks[w * 256 + 0 * 64 + l] = v0;
  ks[w * 256 + 1 * 64 + l] = v1;
  ks[w * 256 + 2 * 64 + l] = v2;
  ks[w * 256 + 3 * 64 + l] = v3;
  __syncthreads();
  const int pw = w ^ wm;
  u64 p0 = ks[pw * 256 + 0 * 64 + l];
  u64 p1 = ks[pw * 256 + 1 * 64 + l];
  u64 p2 = ks[pw * 256 + 2 * 64 + l];
  u64 p3 = ks[pw * 256 + 3 * 64 + l];
  bool km = (up == ((w & wm) == 0));
  v0 = ((v0 > p0) == km) ? v0 : p0;
  v1 = ((v1 > p1) == km) ? v1 : p1;
  v2 = ((v2 > p2) == km) ? v2 : p2;
  v3 = ((v3 > p3) == km) ? v3 : p3;
  __syncthreads();
}

// K1: fused score + per-chunk bitonic sort v2 — 4 keys/thread in registers,
// j<=2 in-thread, j=4..128 via shfl_xor, only j=256/512 through LDS
// (6 barriers total vs 55). Same comparator network => bit-identical output.
__global__ __launch_bounds__(256) void k_sort(const float* __restrict__ confs,
                                              u64* __restrict__ keyG) {
  const int b = blockIdx.x / NCH;
  const int c = blockIdx.x % NCH;
  const int t = threadIdx.x;
  const int l = t & 63;
  const int w = t >> 6;
  const int i0 = w * 256 + l * 4;
  __shared__ u64 ks[KTOP];
  const float4* cf4 = (const float4*)((const float2*)confs + (size_t)b * NPRI + c * KTOP);
  float4 f0 = cf4[i0 >> 1];
  float4 f1 = cf4[(i0 >> 1) + 1];
  u64 v0 = mkkey(f0.x, f0.y, c * KTOP + i0 + 0);
  u64 v1 = mkkey(f0.z, f0.w, c * KTOP + i0 + 1);
  u64 v2 = mkkey(f1.x, f1.y, c * KTOP + i0 + 2);
  u64 v3 = mkkey(f1.z, f1.w, c * KTOP + i0 + 3);
  // k=2: pair dirs depend on slot bit 1
  cex2(v0, v1, true); cex2(v2, v3, false);
  // k=4
  { bool up = ((i0 & 4) == 0); bm_low(v0, v1, v2, v3, l, up, 2); }
  // k=8..256: all lane/register stages
  for (int k = 8; k <= 256; k <<= 1) {
    bool up = ((i0 & k) == 0);
    bm_low(v0, v1, v2, v3, l, up, k >> 1);
  }
  // k=512: j=256 LDS, then j<=128
  { bool up = ((i0 & 512) == 0);
    bm_lds(ks, v0, v1, v2, v3, l, w, 1, up);
    bm_low(v0, v1, v2, v3, l, up, 128); }
  // k=1024: j=512,256 LDS, then j<=128 (up=true everywhere)
  bm_lds(ks, v0, v1, v2, v3, l, w, 2, true);
  bm_lds(ks, v0, v1, v2, v3, l, w, 1, true);
  bm_low(v0, v1, v2, v3, l, true, 128);
  u64* dst = keyG + (size_t)b * NPRI + (size_t)c * KTOP;
  ulonglong2 s01; s01.x = v0; s01.y = v1;
  ulonglong2 s23; s23.x = v2; s23.y = v3;
  *(ulonglong2*)&dst[i0] = s01;
  *(ulonglong2*)&dst[i0 + 2] = s23;
}

// K2: 3 blocks/image: serially merge 7 runs -> top-1024, register form.
// Half-cleaner = elementwise max vs reversed run (pure registers); clean =
// 2 LDS stages + shuffle/register stages. Same network as r17-validated code.
__global__ __launch_bounds__(256) void k_merge7(const u64* __restrict__ keyG,
                                                u64* __restrict__ midG) {
  const int b = blockIdx.x / 3;
  const int p3 = blockIdx.x % 3;
  const int t = threadIdx.x;
  const int l = t & 63;
  const int w = t >> 6;
  const int i0 = w * 256 + l * 4;
  __shared__ u64 ks[KTOP];
  const u64* src = keyG + ((size_t)b * NCH + p3 * 7) * KTOP;
  u64 v0 = src[i0 + 0], v1 = src[i0 + 1], v2 = src[i0 + 2], v3 = src[i0 + 3];
  for (int c = 1; c < 7; c++) {
    // B[i] = run[1023-i] (ascending); item i0+s at src[c*K + 1023-i0-s]
    const u64* sb = src + (size_t)c * KTOP + (KTOP - 4) - i0;
    u64 b3 = sb[0], b2 = sb[1], b1 = sb[2], b0 = sb[3];
    if (b0 > v0) v0 = b0;              // half-cleaner
    if (b1 > v1) v1 = b1;
    if (b2 > v2) v2 = b2;
    if (b3 > v3) v3 = b3;
    bm_lds(ks, v0, v1, v2, v3, l, w, 2, true);   // j=512
    bm_lds(ks, v0, v1, v2, v3, l, w, 1, true);   // j=256
    bm_low(v0, v1, v2, v3, l, true, 128);        // j=128..1
  }
  u64* d = midG + ((size_t)b * 3 + p3) * KTOP;
  ulonglong2 s01; s01.x = v0; s01.y = v1;
  ulonglong2 s23; s23.x = v2; s23.y = v3;
  *(ulonglong2*)&d[i0] = s01;
  *(ulonglong2*)&d[i0 + 2] = s23;
}

// K3: per image: merge 3 mids (register form) -> top-1024 in LDS, then the
// validated decode + valid-ballot loop (unchanged).
__global__ __launch_bounds__(256) void k_merge3(const u64* __restrict__ midG,
                                                const float* __restrict__ locs,
                                                const float* __restrict__ priors,
                                                float* __restrict__ boxF,
                                                float* __restrict__ scoreF,
                                                u64* __restrict__ validW) {
  const int b = blockIdx.x;
  const int t = threadIdx.x;
  const int l = t & 63;
  const int w = t >> 6;
  const int i0 = w * 256 + l * 4;
  __shared__ u64 ks[KTOP];
  const u64* src = midG + (size_t)b * 3 * KTOP;
  u64 v0 = src[i0 + 0], v1 = src[i0 + 1], v2 = src[i0 + 2], v3 = src[i0 + 3];
  for (int c = 1; c < 3; c++) {
    const u64* sb = src + (size_t)c * KTOP + (KTOP - 4) - i0;
    u64 b3 = sb[0], b2 = sb[1], b1 = sb[2], b0 = sb[3];
    if (b0 > v0) v0 = b0;
    if (b1 > v1) v1 = b1;
    if (b2 > v2) v2 = b2;
    if (b3 > v3) v3 = b3;
    bm_lds(ks, v0, v1, v2, v3, l, w, 2, true);
    bm_lds(ks, v0, v1, v2, v3, l, w, 1, true);
    bm_low(v0, v1, v2, v3, l, true, 128);
  }
  ks[i0 + 0] = v0; ks[i0 + 1] = v1; ks[i0 + 2] = v2; ks[i0 + 3] = v3;
  __syncthreads();
  // decode top-1024: f32-stepwise (identical expressions to validated round 7)
  for (int i = t; i < KTOP; i += 256) {
    u64 K = ks[i];
    float sv = __uint_as_float((u32)(K >> 15));
    int idx = NPRI - 1 - (int)(K & 0x7FFFu);
    float4 lo = ((const float4*)locs)[(size_t)b * NPRI + idx];
    float4 pr = ((const float4*)priors)[idx];
    float cx = pr.x + (lo.x * 0.1f) * pr.z;
    float cy = pr.y + (lo.y * 0.1f) * pr.w;
    float wd = pr.z * crexpf(lo.z * 0.2f);
    float ht = pr.w * crexpf(lo.w * 0.2f);
    float x1 = cx - wd * 0.5f;
    float y1 = cy - ht * 0.5f;
    float x2 = x1 + wd;
    float y2 = y1 + ht;
    size_t o = (size_t)b * KTOP + i;
    boxF[o * 4 + 0] = x1;
    boxF[o * 4 + 1] = y1;
    boxF[o * 4 + 2] = x2;
    boxF[o * 4 + 3] = y2;
    scoreF[o] = sv;
    u64 mask = __ballot(sv > 0.5f);       // wave covers group i>>6
    if ((t & 63) == 0) validW[(size_t)b * 16 + (i >> 6)] = mask;
  }
}

// K4: upper-triangle suppression bitmask (r13/r17-validated IoU bits), packed
// rows + XCD-affinity grid (unchanged).
__global__ __launch_bounds__(256) void k_iou(const float* __restrict__ boxF,
                                             u64* __restrict__ supP) {
  const int bid = blockIdx.x;
  const int x8 = bid & 7;
  const int q = bid >> 3;
  const int bslot = q / 40;
  int task = q - bslot * 40;           // 0..39
  const int b = bslot * 8 + x8;        // image
  int g = 0, base = 0;
  for (int gg = 0; gg < 16; gg++) {
    int cg = (16 - gg + 3) >> 2;
    if (task < base + cg) { g = gg; break; }
    base += cg;
  }
  const int c = task - base;
  const int w0 = g + 4 * c;            // first word of this chunk
  __shared__ float4 BXS[256];
  __shared__ float ARS[256];
  const float4* bb = (const float4*)(boxF + (size_t)b * KTOP * 4);
  {
    int j = w0 * 64 + threadIdx.x;
    if (j < KTOP) {
      float4 v = bb[j];
      BXS[threadIdx.x] = v;
      ARS[threadIdx.x] = fmaxf(v.z - v.x, 0.0f) * fmaxf(v.w - v.y, 0.0f);
    }
  }
  const int r = threadIdx.x & 63;
  const int v = threadIdx.x >> 6;      // wave 0..3
  const int i = g * 64 + r;
  float4 bi = bb[i];
  float a = fmaxf(bi.z - bi.x, 0.0f) * fmaxf(bi.w - bi.y, 0.0f);
  __syncthreads();
  const int w = w0 + v;
  if (w < 16) {
    u64 word = 0;
    const int lbase = v * 64;
    for (int jb = 0; jb < 64; jb++) {
      int lj = lbase + jb;
      float4 bj = BXS[lj];             // broadcast (w uniform in wave)
      float aj = ARS[lj];
      float lx = fmaxf(bi.x, bj.x);
      float ly = fmaxf(bi.y, bj.y);
      float rx = fminf(bi.z, bj.z);
      float ry = fminf(bi.w, bj.w);
      float iw = fmaxf(rx - lx, 0.0f);
      float ih = fmaxf(ry - ly, 0.0f);
      float inter = iw * ih;
      float uni = (a + aj) - inter;
      float iou = inter / fmaxf(uni, 1e-9f);
      if (iou > 0.4f) word |= (1ULL << jb);
    }
    if (w == g) word &= (r == 63) ? 0ULL : (~0ULL << (r + 1));   // j > i
    supP[(size_t)b * SUPW + supBase(g) + (size_t)r * (16 - g) + (w - g)] = word;
  }
}

// K5: greedy scan v7 — frontier-fixpoint NMS (r18-validated). Greedy NMS ==
// iterate frontier = alive & ~(OR rows of alive); keep |= frontier;
// alive &= ~frontier & ~(OR rows of frontier) until empty.
__global__ __launch_bounds__(256) void k_scan(const u64* __restrict__ supP,
                                              const u64* __restrict__ validW,
                                              const float* __restrict__ boxF,
                                              const float* __restrict__ scoreF,
                                              float* __restrict__ out) {
  extern __shared__ u64 rows[];        // SUPW u64 = 69632 B
  const int b = blockIdx.x;
  const int t = threadIdx.x;
  const int lane = t & 63;
  const int wv = t >> 6;               // wave 0..3
  __shared__ u64 aliveA[16], aliveB[16], supW[16], keepW[16];
  __shared__ int contF[2];
  const u64* supB = supP + (size_t)b * SUPW;
  // async bulk stage: 68 chunks x 1 KB (unchanged, r17-validated)
  {
    const unsigned char* gb = (const unsigned char*)supB;
    unsigned char* lb = (unsigned char*)rows;
    for (int c = wv; c < 68; c += 4) {
      int off = c << 10;
      __builtin_amdgcn_global_load_lds(
          (const __attribute__((address_space(1))) unsigned int*)(gb + off + lane * 16),
          (__attribute__((address_space(3))) unsigned int*)(lb + off),
          16, 0, 0);
    }
  }
  if (t < 16) { aliveA[t] = validW[(size_t)b * 16 + t]; keepW[t] = 0; }
  if (t == 0) contF[0] = 0;
  __syncthreads();                     // drains vmcnt; init visible

  u64* cur = aliveA;
  u64* nxt = aliveB;
  const int w = t >> 4;                // owned suppression word 0..15
  const int k = t & 15;                // lane within word-team
  for (int round = 0;; ++round) {
    const int p = round & 1;
    // region 1: supW[w] = OR over alive rows i (g(i) <= w) of their word w
    u64 acc = 0;
    for (int g = 0; g <= w; ++g) {
      int base = supBase(g) + (w - g);
      int rl = 16 - g;
      u64 am = cur[g];
      for (int r = k; r < 64; r += 16)
        if ((am >> r) & 1) acc |= rows[base + r * rl];
    }
    acc |= __shfl_xor(acc, 1);
    acc |= __shfl_xor(acc, 2);
    acc |= __shfl_xor(acc, 4);
    acc |= __shfl_xor(acc, 8);
    if (k == 0) supW[w] = acc;
    __syncthreads();                   // A: supW stable
    // region 2: removed-by-frontier sweep + state update (writes go to nxt)
    u64 acc2 = 0;
    for (int g = 0; g <= w; ++g) {
      int base = supBase(g) + (w - g);
      int rl = 16 - g;
      u64 fm = cur[g] & ~supW[g];      // frontier bits of group g
      for (int r = k; r < 64; r += 16)
        if ((fm >> r) & 1) acc2 |= rows[base + r * rl];
    }
    acc2 |= __shfl_xor(acc2, 1);
    acc2 |= __shfl_xor(acc2, 2);
    acc2 |= __shfl_xor(acc2, 4);
    acc2 |= __shfl_xor(acc2, 8);
    if (k == 0) {
      u64 a = cur[w];
      u64 f = a & ~supW[w];
      keepW[w] |= f;
      u64 na = a & ~(f | acc2);
      nxt[w] = na;
      if (na) contF[p] = 1;            // benign same-value race
    }
    if (t == 0) contF[p ^ 1] = 0;      // pre-zero next round's flag
    __syncthreads();                   // B: keepW/nxt/contF stable
    if (!contF[p]) break;              // uniform: all threads read same value
    u64* tmp = cur; cur = nxt; nxt = tmp;
  }
  const float* bb = boxF + (size_t)b * KTOP * 4;
  const float* sc = scoreF + (size_t)b * KTOP;
  const float4* bb4 = (const float4*)bb;
  for (int i = t; i < KTOP; i += 256) {
    float kf = ((keepW[i >> 6] >> (i & 63)) & 1ULL) ? 1.0f : 0.0f;
    float4 bv = bb4[i];
    size_t o5 = ((size_t)b * KTOP + i) * 5;
    out[o5 + 0] = bv.x * kf;
    out[o5 + 1] = bv.y * kf;
    out[o5 + 2] = bv.z * kf;
    out[o5 + 3] = bv.w * kf;
    out[o5 + 4] = sc[i] * kf;
    out[(size_t)BATCH * KTOP * 5 + (size_t)b * KTOP + i] = kf;
  }
}

extern "C" void kernel_launch(void* const* d_in, const int* in_sizes, int n_in,
                              void* d_out, int out_size, void* d_ws, size_t ws_size,
                              hipStream_t stream) {
  const float* locs = nullptr;
  const float* confs = nullptr;
  const float* priors = nullptr;
  for (int i = 0; i < n_in; i++) {
    if (in_sizes[i] == BATCH * NPRI * 4) locs = (const float*)d_in[i];
    else if (in_sizes[i] == BATCH * NPRI * 2) confs = (const float*)d_in[i];
    else if (in_sizes[i] == NPRI * 4) priors = (const float*)d_in[i];
  }
  float* out = (float*)d_out;   // f32: [B,K,5] dets ++ [B,K] keep

  char* ws = (char*)d_ws;
  size_t off = 0;
  u64* keyG = (u64*)(ws + off);          // B*21*1024*8 = 11,010,048
  u64* supP = (u64*)(ws + off);          // alias: keyG dead after k_merge7 (4,456,448)
  off += (size_t)BATCH * NCH * KTOP * 8;
  u64* midG = (u64*)(ws + off);          off += (size_t)BATCH * 3 * KTOP * 8;   // 1,572,864
  float* boxF = (float*)(ws + off);      off += (size_t)BATCH * KTOP * 4 * 4;   // 1,048,576
  float* scoreF = (float*)(ws + off);    off += (size_t)BATCH * KTOP * 4;       //   262,144
  u64* validW = (u64*)(ws + off);        off += (size_t)BATCH * 16 * 8;         //     8,192
  // total ~13.9 MB

  k_sort<<<BATCH * NCH, 256, 0, stream>>>(confs, keyG);
  k_merge7<<<BATCH * 3, 256, 0, stream>>>(keyG, midG);
  k_merge3<<<BATCH, 256, 0, stream>>>(midG, locs, priors, boxF, scoreF, validW);
  k_iou<<<2560, 256, 0, stream>>>(boxF, supP);
  k_scan<<<BATCH, 256, SUPW * 8, stream>>>(supP, validW, boxF, scoreF, out);
}

// Round 3
// 168.107 us; speedup vs baseline: 1.5850x; 1.0904x over previous
//
#include <hip/hip_runtime.h>

#define NPRI 21504
#define BATCH 64
#define KTOP 1024
#define NCH 21
#define SUPW 8704   // packed upper-triangle words/image = 64 * sum(16-g) = 64*136

typedef unsigned long long u64;
typedef unsigned int u32;

// correctly-rounded f32 exp via f64 libm exp (validated: absmax 3e-8)
__device__ __forceinline__ float crexpf(float x) { return (float)exp((double)x); }

// packed row base for group g: 64 * (16g - g(g-1)/2)
__device__ __forceinline__ int supBase(int g) {
  return 64 * (16 * g - (g * (g - 1)) / 2);
}

// Key packing (validated): key = (score_bits<<15) | (NPRI-1-idx). Unique keys;
// desc u64 order == (score desc, idx asc) == lax.top_k stable order => any
// correct top-1024 structure is bit-exact.
__device__ __forceinline__ u64 mkkey(float x, float y, int idx) {
  float m = fmaxf(x, y);
  float e0 = crexpf(x - m);
  float e1 = crexpf(y - m);
  float s = e1 / (e0 + e1);          // exact f32 steps (validated)
  return ((u64)__float_as_uint(s) << 15) | (u64)(NPRI - 1 - idx);
}

// ---- register/shuffle bitonic primitives (r19-validated) -------------------
// Item index i = w*256 + l*4 + s  (wave bits 9:8, lane bits 7:2, slot bits 1:0).

__device__ __forceinline__ u64 shflx64(u64 v, int m) {
  int lo = __shfl_xor((int)(u32)v, m, 64);
  int hi = __shfl_xor((int)(u32)(v >> 32), m, 64);
  return ((u64)(u32)hi << 32) | (u64)(u32)lo;
}

__device__ __forceinline__ void cex2(u64& lo, u64& hi, bool up) {
  u64 a = lo, b = hi;
  bool g = a > b;
  u64 mx = g ? a : b, mn = g ? b : a;
  lo = up ? mx : mn;
  hi = up ? mn : mx;
}

__device__ __forceinline__ void cexs(u64& v, int m, bool keep_max) {
  u64 pv = shflx64(v, m);
  v = ((v > pv) == keep_max) ? v : pv;
}

// stages j = jmax..1 (jmax<=128) of a bitonic merge, direction `up` uniform
// across the thread's 4 slots (holds for all k>=4 call sites).
__device__ __forceinline__ void bm_low(u64& v0, u64& v1, u64& v2, u64& v3,
                                       int l, bool up, int jmax) {
  for (int m = jmax >> 2; m >= 1; m >>= 1) {   // j = 4*m (lane-xor stages)
    bool km = (up == ((l & m) == 0));
    cexs(v0, m, km); cexs(v1, m, km); cexs(v2, m, km); cexs(v3, m, km);
  }
  cex2(v0, v2, up); cex2(v1, v3, up);          // j = 2
  cex2(v0, v1, up); cex2(v2, v3, up);          // j = 1
}

// one cross-wave LDS exchange stage: j = 256*wm, direction `up` per-thread
// (uniform within a wave). Layout lane-low: addr = w*256 + s*64 + l.
__device__ __forceinline__ void bm_lds(u64* ks, u64& v0, u64& v1, u64& v2, u64& v3,
                                       int l, int w, int wm, bool up) {
  ks[w * 256 + 0 * 64 + l] = v0;
  ks[w * 256 + 1 * 64 + l] = v1;
  ks[w * 256 + 2 * 64 + l] = v2;
  ks[w * 256 + 3 * 64 + l] = v3;
  __syncthreads();
  const int pw = w ^ wm;
  u64 p0 = ks[pw * 256 + 0 * 64 + l];
  u64 p1 = ks[pw * 256 + 1 * 64 + l];
  u64 p2 = ks[pw * 256 + 2 * 64 + l];
  u64 p3 = ks[pw * 256 + 3 * 64 + l];
  bool km = (up == ((w & wm) == 0));
  v0 = ((v0 > p0) == km) ? v0 : p0;
  v1 = ((v1 > p1) == km) ? v1 : p1;
  v2 = ((v2 > p2) == km) ? v2 : p2;
  v3 = ((v3 > p3) == km) ? v3 : p3;
  __syncthreads();
}

// K1: fused score + per-chunk bitonic sort v2 (r19-validated register form).
__global__ __launch_bounds__(256) void k_sort(const float* __restrict__ confs,
                                              u64* __restrict__ keyG) {
  const int b = blockIdx.x / NCH;
  const int c = blockIdx.x % NCH;
  const int t = threadIdx.x;
  const int l = t & 63;
  const int w = t >> 6;
  const int i0 = w * 256 + l * 4;
  __shared__ u64 ks[KTOP];
  const float4* cf4 = (const float4*)((const float2*)confs + (size_t)b * NPRI + c * KTOP);
  float4 f0 = cf4[i0 >> 1];
  float4 f1 = cf4[(i0 >> 1) + 1];
  u64 v0 = mkkey(f0.x, f0.y, c * KTOP + i0 + 0);
  u64 v1 = mkkey(f0.z, f0.w, c * KTOP + i0 + 1);
  u64 v2 = mkkey(f1.x, f1.y, c * KTOP + i0 + 2);
  u64 v3 = mkkey(f1.z, f1.w, c * KTOP + i0 + 3);
  // k=2: pair dirs depend on slot bit 1
  cex2(v0, v1, true); cex2(v2, v3, false);
  // k=4
  { bool up = ((i0 & 4) == 0); bm_low(v0, v1, v2, v3, l, up, 2); }
  // k=8..256: all lane/register stages
  for (int k = 8; k <= 256; k <<= 1) {
    bool up = ((i0 & k) == 0);
    bm_low(v0, v1, v2, v3, l, up, k >> 1);
  }
  // k=512: j=256 LDS, then j<=128
  { bool up = ((i0 & 512) == 0);
    bm_lds(ks, v0, v1, v2, v3, l, w, 1, up);
    bm_low(v0, v1, v2, v3, l, up, 128); }
  // k=1024: j=512,256 LDS, then j<=128 (up=true everywhere)
  bm_lds(ks, v0, v1, v2, v3, l, w, 2, true);
  bm_lds(ks, v0, v1, v2, v3, l, w, 1, true);
  bm_low(v0, v1, v2, v3, l, true, 128);
  u64* dst = keyG + (size_t)b * NPRI + (size_t)c * KTOP;
  ulonglong2 s01; s01.x = v0; s01.y = v1;
  ulonglong2 s23; s23.x = v2; s23.y = v3;
  *(ulonglong2*)&dst[i0] = s01;
  *(ulonglong2*)&dst[i0 + 2] = s23;
}

// K2: 3 blocks/image: serially merge 7 runs -> top-1024 (r19-validated).
__global__ __launch_bounds__(256) void k_merge7(const u64* __restrict__ keyG,
                                                u64* __restrict__ midG) {
  const int b = blockIdx.x / 3;
  const int p3 = blockIdx.x % 3;
  const int t = threadIdx.x;
  const int l = t & 63;
  const int w = t >> 6;
  const int i0 = w * 256 + l * 4;
  __shared__ u64 ks[KTOP];
  const u64* src = keyG + ((size_t)b * NCH + p3 * 7) * KTOP;
  u64 v0 = src[i0 + 0], v1 = src[i0 + 1], v2 = src[i0 + 2], v3 = src[i0 + 3];
  for (int c = 1; c < 7; c++) {
    // B[i] = run[1023-i] (ascending); item i0+s at src[c*K + 1023-i0-s]
    const u64* sb = src + (size_t)c * KTOP + (KTOP - 4) - i0;
    u64 b3 = sb[0], b2 = sb[1], b1 = sb[2], b0 = sb[3];
    if (b0 > v0) v0 = b0;              // half-cleaner
    if (b1 > v1) v1 = b1;
    if (b2 > v2) v2 = b2;
    if (b3 > v3) v3 = b3;
    bm_lds(ks, v0, v1, v2, v3, l, w, 2, true);   // j=512
    bm_lds(ks, v0, v1, v2, v3, l, w, 1, true);   // j=256
    bm_low(v0, v1, v2, v3, l, true, 128);        // j=128..1
  }
  u64* d = midG + ((size_t)b * 3 + p3) * KTOP;
  ulonglong2 s01; s01.x = v0; s01.y = v1;
  ulonglong2 s23; s23.x = v2; s23.y = v3;
  *(ulonglong2*)&d[i0] = s01;
  *(ulonglong2*)&d[i0 + 2] = s23;
}

// K3: per image: merge 3 mids (register form) -> top-1024 in LDS, then the
// validated decode + valid-ballot loop (r19-validated).
__global__ __launch_bounds__(256) void k_merge3(const u64* __restrict__ midG,
                                                const float* __restrict__ locs,
                                                const float* __restrict__ priors,
                                                float* __restrict__ boxF,
                                                float* __restrict__ scoreF,
                                                u64* __restrict__ validW) {
  const int b = blockIdx.x;
  const int t = threadIdx.x;
  const int l = t & 63;
  const int w = t >> 6;
  const int i0 = w * 256 + l * 4;
  __shared__ u64 ks[KTOP];
  const u64* src = midG + (size_t)b * 3 * KTOP;
  u64 v0 = src[i0 + 0], v1 = src[i0 + 1], v2 = src[i0 + 2], v3 = src[i0 + 3];
  for (int c = 1; c < 3; c++) {
    const u64* sb = src + (size_t)c * KTOP + (KTOP - 4) - i0;
    u64 b3 = sb[0], b2 = sb[1], b1 = sb[2], b0 = sb[3];
    if (b0 > v0) v0 = b0;
    if (b1 > v1) v1 = b1;
    if (b2 > v2) v2 = b2;
    if (b3 > v3) v3 = b3;
    bm_lds(ks, v0, v1, v2, v3, l, w, 2, true);
    bm_lds(ks, v0, v1, v2, v3, l, w, 1, true);
    bm_low(v0, v1, v2, v3, l, true, 128);
  }
  ks[i0 + 0] = v0; ks[i0 + 1] = v1; ks[i0 + 2] = v2; ks[i0 + 3] = v3;
  __syncthreads();
  // decode top-1024: f32-stepwise (identical expressions to validated round 7)
  for (int i = t; i < KTOP; i += 256) {
    u64 K = ks[i];
    float sv = __uint_as_float((u32)(K >> 15));
    int idx = NPRI - 1 - (int)(K & 0x7FFFu);
    float4 lo = ((const float4*)locs)[(size_t)b * NPRI + idx];
    float4 pr = ((const float4*)priors)[idx];
    float cx = pr.x + (lo.x * 0.1f) * pr.z;
    float cy = pr.y + (lo.y * 0.1f) * pr.w;
    float wd = pr.z * crexpf(lo.z * 0.2f);
    float ht = pr.w * crexpf(lo.w * 0.2f);
    float x1 = cx - wd * 0.5f;
    float y1 = cy - ht * 0.5f;
    float x2 = x1 + wd;
    float y2 = y1 + ht;
    size_t o = (size_t)b * KTOP + i;
    boxF[o * 4 + 0] = x1;
    boxF[o * 4 + 1] = y1;
    boxF[o * 4 + 2] = x2;
    boxF[o * 4 + 3] = y2;
    scoreF[o] = sv;
    u64 mask = __ballot(sv > 0.5f);       // wave covers group i>>6
    if ((t & 63) == 0) validW[(size_t)b * 16 + (i >> 6)] = mask;
  }
}

// K4: upper-triangle suppression bitmask (r13/r17-validated IoU bits), packed
// rows + XCD-affinity grid (unchanged).
__global__ __launch_bounds__(256) void k_iou(const float* __restrict__ boxF,
                                             u64* __restrict__ supP) {
  const int bid = blockIdx.x;
  const int x8 = bid & 7;
  const int q = bid >> 3;
  const int bslot = q / 40;
  int task = q - bslot * 40;           // 0..39
  const int b = bslot * 8 + x8;        // image
  int g = 0, base = 0;
  for (int gg = 0; gg < 16; gg++) {
    int cg = (16 - gg + 3) >> 2;
    if (task < base + cg) { g = gg; break; }
    base += cg;
  }
  const int c = task - base;
  const int w0 = g + 4 * c;            // first word of this chunk
  __shared__ float4 BXS[256];
  __shared__ float ARS[256];
  const float4* bb = (const float4*)(boxF + (size_t)b * KTOP * 4);
  {
    int j = w0 * 64 + threadIdx.x;
    if (j < KTOP) {
      float4 v = bb[j];
      BXS[threadIdx.x] = v;
      ARS[threadIdx.x] = fmaxf(v.z - v.x, 0.0f) * fmaxf(v.w - v.y, 0.0f);
    }
  }
  const int r = threadIdx.x & 63;
  const int v = threadIdx.x >> 6;      // wave 0..3
  const int i = g * 64 + r;
  float4 bi = bb[i];
  float a = fmaxf(bi.z - bi.x, 0.0f) * fmaxf(bi.w - bi.y, 0.0f);
  __syncthreads();
  const int w = w0 + v;
  if (w < 16) {
    u64 word = 0;
    const int lbase = v * 64;
    for (int jb = 0; jb < 64; jb++) {
      int lj = lbase + jb;
      float4 bj = BXS[lj];             // broadcast (w uniform in wave)
      float aj = ARS[lj];
      float lx = fmaxf(bi.x, bj.x);
      float ly = fmaxf(bi.y, bj.y);
      float rx = fminf(bi.z, bj.z);
      float ry = fminf(bi.w, bj.w);
      float iw = fmaxf(rx - lx, 0.0f);
      float ih = fmaxf(ry - ly, 0.0f);
      float inter = iw * ih;
      float uni = (a + aj) - inter;
      float iou = inter / fmaxf(uni, 1e-9f);
      if (iou > 0.4f) word |= (1ULL << jb);
    }
    if (w == g) word &= (r == 63) ? 0ULL : (~0ULL << (r + 1));   // j > i
    supP[(size_t)b * SUPW + supBase(g) + (size_t)r * (16 - g) + (w - g)] = word;
  }
}

// K5: greedy scan v8 — frontier-fixpoint NMS with UNCONDITIONAL masked LDS
// reads. v7's `if (alive-bit) acc |= rows[..]` put every ds_read under a
// divergent branch -> serialized ~120-cyc LDS latencies (no batching). Now
// loads are straight-line (address clamped for inactive g>w iterations,
// result ANDed with a full/zero mask) so the compiler pipelines ~16
// independent ds_read_b64 per unroll window. Identical OR-reduction bits.
__global__ __launch_bounds__(256) void k_scan(const u64* __restrict__ supP,
                                              const u64* __restrict__ validW,
                                              const float* __restrict__ boxF,
                                              const float* __restrict__ scoreF,
                                              float* __restrict__ out) {
  extern __shared__ u64 rows[];        // SUPW u64 = 69632 B
  const int b = blockIdx.x;
  const int t = threadIdx.x;
  const int lane = t & 63;
  const int wv = t >> 6;               // wave 0..3
  __shared__ u64 aliveA[16], aliveB[16], supW[16], keepW[16];
  __shared__ int contF[2];
  const u64* supB = supP + (size_t)b * SUPW;
  // async bulk stage: 68 chunks x 1 KB (unchanged, r17-validated)
  {
    const unsigned char* gb = (const unsigned char*)supB;
    unsigned char* lb = (unsigned char*)rows;
    for (int c = wv; c < 68; c += 4) {
      int off = c << 10;
      __builtin_amdgcn_global_load_lds(
          (const __attribute__((address_space(1))) unsigned int*)(gb + off + lane * 16),
          (__attribute__((address_space(3))) unsigned int*)(lb + off),
          16, 0, 0);
    }
  }
  if (t < 16) { aliveA[t] = validW[(size_t)b * 16 + t]; keepW[t] = 0; }
  if (t == 0) contF[0] = 0;
  __syncthreads();                     // drains vmcnt; init visible

  u64* cur = aliveA;
  u64* nxt = aliveB;
  const int w = t >> 4;                // owned suppression word 0..15
  const int k = t & 15;                // lane within word-team
  for (int round = 0;; ++round) {
    const int p = round & 1;
    // region 1: supW[w] = OR over alive rows i (g(i) <= w) of their word w
    u64 acc = 0;
#pragma unroll 4
    for (int g = 0; g < 16; ++g) {
      const bool act = (g <= w);
      const int base = act ? (supBase(g) + (w - g)) : 0;
      const int rl = 16 - g;
      const u64 am = cur[g];
#pragma unroll
      for (int mi = 0; mi < 4; ++mi) {
        const int r = k + 16 * mi;
        u64 rowv = rows[base + r * rl];                 // unconditional load
        u64 msk = (act && ((am >> r) & 1)) ? ~0ULL : 0ULL;
        acc |= rowv & msk;
      }
    }
    acc |= shflx64(acc, 1);
    acc |= shflx64(acc, 2);
    acc |= shflx64(acc, 4);
    acc |= shflx64(acc, 8);
    if (k == 0) supW[w] = acc;
    __syncthreads();                   // A: supW stable
    // region 2: removed-by-frontier sweep + state update (writes go to nxt)
    u64 acc2 = 0;
#pragma unroll 4
    for (int g = 0; g < 16; ++g) {
      const bool act = (g <= w);
      const int base = act ? (supBase(g) + (w - g)) : 0;
      const int rl = 16 - g;
      const u64 fm = cur[g] & ~supW[g];      // frontier bits of group g
#pragma unroll
      for (int mi = 0; mi < 4; ++mi) {
        const int r = k + 16 * mi;
        u64 rowv = rows[base + r * rl];                 // unconditional load
        u64 msk = (act && ((fm >> r) & 1)) ? ~0ULL : 0ULL;
        acc2 |= rowv & msk;
      }
    }
    acc2 |= shflx64(acc2, 1);
    acc2 |= shflx64(acc2, 2);
    acc2 |= shflx64(acc2, 4);
    acc2 |= shflx64(acc2, 8);
    if (k == 0) {
      u64 a = cur[w];
      u64 f = a & ~supW[w];
      keepW[w] |= f;
      u64 na = a & ~(f | acc2);
      nxt[w] = na;
      if (na) contF[p] = 1;            // benign same-value race
    }
    if (t == 0) contF[p ^ 1] = 0;      // pre-zero next round's flag
    __syncthreads();                   // B: keepW/nxt/contF stable
    if (!contF[p]) break;              // uniform: all threads read same value
    u64* tmp = cur; cur = nxt; nxt = tmp;
  }
  const float* bb = boxF + (size_t)b * KTOP * 4;
  const float* sc = scoreF + (size_t)b * KTOP;
  const float4* bb4 = (const float4*)bb;
  for (int i = t; i < KTOP; i += 256) {
    float kf = ((keepW[i >> 6] >> (i & 63)) & 1ULL) ? 1.0f : 0.0f;
    float4 bv = bb4[i];
    size_t o5 = ((size_t)b * KTOP + i) * 5;
    out[o5 + 0] = bv.x * kf;
    out[o5 + 1] = bv.y * kf;
    out[o5 + 2] = bv.z * kf;
    out[o5 + 3] = bv.w * kf;
    out[o5 + 4] = sc[i] * kf;
    out[(size_t)BATCH * KTOP * 5 + (size_t)b * KTOP + i] = kf;
  }
}

extern "C" void kernel_launch(void* const* d_in, const int* in_sizes, int n_in,
                              void* d_out, int out_size, void* d_ws, size_t ws_size,
                              hipStream_t stream) {
  const float* locs = nullptr;
  const float* confs = nullptr;
  const float* priors = nullptr;
  for (int i = 0; i < n_in; i++) {
    if (in_sizes[i] == BATCH * NPRI * 4) locs = (const float*)d_in[i];
    else if (in_sizes[i] == BATCH * NPRI * 2) confs = (const float*)d_in[i];
    else if (in_sizes[i] == NPRI * 4) priors = (const float*)d_in[i];
  }
  float* out = (float*)d_out;   // f32: [B,K,5] dets ++ [B,K] keep

  char* ws = (char*)d_ws;
  size_t off = 0;
  u64* keyG = (u64*)(ws + off);          // B*21*1024*8 = 11,010,048
  u64* supP = (u64*)(ws + off);          // alias: keyG dead after k_merge7 (4,456,448)
  off += (size_t)BATCH * NCH * KTOP * 8;
  u64* midG = (u64*)(ws + off);          off += (size_t)BATCH * 3 * KTOP * 8;   // 1,572,864
  float* boxF = (float*)(ws + off);      off += (size_t)BATCH * KTOP * 4 * 4;   // 1,048,576
  float* scoreF = (float*)(ws + off);    off += (size_t)BATCH * KTOP * 4;       //   262,144
  u64* validW = (u64*)(ws + off);        off += (size_t)BATCH * 16 * 8;         //     8,192
  // total ~13.9 MB

  k_sort<<<BATCH * NCH, 256, 0, stream>>>(confs, keyG);
  k_merge7<<<BATCH * 3, 256, 0, stream>>>(keyG, midG);
  k_merge3<<<BATCH, 256, 0, stream>>>(midG, locs, priors, boxF, scoreF, validW);
  k_iou<<<2560, 256, 0, stream>>>(boxF, supP);
  k_scan<<<BATCH, 256, SUPW * 8, stream>>>(supP, validW, boxF, scoreF, out);
}

// Round 4
// 167.843 us; speedup vs baseline: 1.5875x; 1.0016x over previous
//
#include <hip/hip_runtime.h>

#define NPRI 21504
#define BATCH 64
#define KTOP 1024
#define NCH 21
#define SUPW 9216   // padded packed upper-triangle words/image = 64 * sum((16-g)|1) = 64*144

typedef unsigned long long u64;
typedef unsigned int u32;

// correctly-rounded f32 exp via f64 libm exp (validated: absmax 3e-8)
__device__ __forceinline__ float crexpf(float x) { return (float)exp((double)x); }

// padded packed layout: group g rows have ODD stride s_g = (16-g)|1 (u64),
// so 16-lane teams reading column w at row stride s_g hit 16 distinct banks
// (k*s mod 16 is a permutation for odd s) -> wave64 b64 at the 4/bank floor.
__device__ __forceinline__ int supStride(int g) { return (16 - g) | 1; }
// base(g) = 64 * sum_{h<g} s_h = 64 * (16g - g(g-1)/2 + ceil(g/2))
__device__ __forceinline__ int supBaseP(int g) {
  return 64 * (16 * g - (g * (g - 1)) / 2 + ((g + 1) >> 1));
}

// Key packing (validated): key = (score_bits<<15) | (NPRI-1-idx). Unique keys;
// desc u64 order == (score desc, idx asc) == lax.top_k stable order => any
// correct top-1024 structure is bit-exact.
__device__ __forceinline__ u64 mkkey(float x, float y, int idx) {
  float m = fmaxf(x, y);
  float e0 = crexpf(x - m);
  float e1 = crexpf(y - m);
  float s = e1 / (e0 + e1);          // exact f32 steps (validated)
  return ((u64)__float_as_uint(s) << 15) | (u64)(NPRI - 1 - idx);
}

// ---- register/shuffle bitonic primitives (r19-validated) -------------------
// Item index i = w*256 + l*4 + s  (wave bits 9:8, lane bits 7:2, slot bits 1:0).

__device__ __forceinline__ u64 shflx64(u64 v, int m) {
  int lo = __shfl_xor((int)(u32)v, m, 64);
  int hi = __shfl_xor((int)(u32)(v >> 32), m, 64);
  return ((u64)(u32)hi << 32) | (u64)(u32)lo;
}

__device__ __forceinline__ void cex2(u64& lo, u64& hi, bool up) {
  u64 a = lo, b = hi;
  bool g = a > b;
  u64 mx = g ? a : b, mn = g ? b : a;
  lo = up ? mx : mn;
  hi = up ? mn : mx;
}

__device__ __forceinline__ void cexs(u64& v, int m, bool keep_max) {
  u64 pv = shflx64(v, m);
  v = ((v > pv) == keep_max) ? v : pv;
}

// stages j = jmax..1 (jmax<=128) of a bitonic merge, direction `up` uniform
// across the thread's 4 slots (holds for all k>=4 call sites).
__device__ __forceinline__ void bm_low(u64& v0, u64& v1, u64& v2, u64& v3,
                                       int l, bool up, int jmax) {
  for (int m = jmax >> 2; m >= 1; m >>= 1) {   // j = 4*m (lane-xor stages)
    bool km = (up == ((l & m) == 0));
    cexs(v0, m, km); cexs(v1, m, km); cexs(v2, m, km); cexs(v3, m, km);
  }
  cex2(v0, v2, up); cex2(v1, v3, up);          // j = 2
  cex2(v0, v1, up); cex2(v2, v3, up);          // j = 1
}

// one cross-wave LDS exchange stage: j = 256*wm, direction `up` per-thread
// (uniform within a wave). Layout lane-low: addr = w*256 + s*64 + l.
__device__ __forceinline__ void bm_lds(u64* ks, u64& v0, u64& v1, u64& v2, u64& v3,
                                       int l, int w, int wm, bool up) {
  ks[w * 256 + 0 * 64 + l] = v0;
  ks[w * 256 + 1 * 64 + l] = v1;
  ks[w * 256 + 2 * 64 + l] = v2;
  ks[w * 256 + 3 * 64 + l] = v3;
  __syncthreads();
  const int pw = w ^ wm;
  u64 p0 = ks[pw * 256 + 0 * 64 + l];
  u64 p1 = ks[pw * 256 + 1 * 64 + l];
  u64 p2 = ks[pw * 256 + 2 * 64 + l];
  u64 p3 = ks[pw * 256 + 3 * 64 + l];
  bool km = (up == ((w & wm) == 0));
  v0 = ((v0 > p0) == km) ? v0 : p0;
  v1 = ((v1 > p1) == km) ? v1 : p1;
  v2 = ((v2 > p2) == km) ? v2 : p2;
  v3 = ((v3 > p3) == km) ? v3 : p3;
  __syncthreads();
}

// K1: fused score + per-chunk bitonic sort v2 (r19-validated register form).
__global__ __launch_bounds__(256) void k_sort(const float* __restrict__ confs,
                                              u64* __restrict__ keyG) {
  const int b = blockIdx.x / NCH;
  const int c = blockIdx.x % NCH;
  const int t = threadIdx.x;
  const int l = t & 63;
  const int w = t >> 6;
  const int i0 = w * 256 + l * 4;
  __shared__ u64 ks[KTOP];
  const float4* cf4 = (const float4*)((const float2*)confs + (size_t)b * NPRI + c * KTOP);
  float4 f0 = cf4[i0 >> 1];
  float4 f1 = cf4[(i0 >> 1) + 1];
  u64 v0 = mkkey(f0.x, f0.y, c * KTOP + i0 + 0);
  u64 v1 = mkkey(f0.z, f0.w, c * KTOP + i0 + 1);
  u64 v2 = mkkey(f1.x, f1.y, c * KTOP + i0 + 2);
  u64 v3 = mkkey(f1.z, f1.w, c * KTOP + i0 + 3);
  // k=2: pair dirs depend on slot bit 1
  cex2(v0, v1, true); cex2(v2, v3, false);
  // k=4
  { bool up = ((i0 & 4) == 0); bm_low(v0, v1, v2, v3, l, up, 2); }
  // k=8..256: all lane/register stages
  for (int k = 8; k <= 256; k <<= 1) {
    bool up = ((i0 & k) == 0);
    bm_low(v0, v1, v2, v3, l, up, k >> 1);
  }
  // k=512: j=256 LDS, then j<=128
  { bool up = ((i0 & 512) == 0);
    bm_lds(ks, v0, v1, v2, v3, l, w, 1, up);
    bm_low(v0, v1, v2, v3, l, up, 128); }
  // k=1024: j=512,256 LDS, then j<=128 (up=true everywhere)
  bm_lds(ks, v0, v1, v2, v3, l, w, 2, true);
  bm_lds(ks, v0, v1, v2, v3, l, w, 1, true);
  bm_low(v0, v1, v2, v3, l, true, 128);
  u64* dst = keyG + (size_t)b * NPRI + (size_t)c * KTOP;
  ulonglong2 s01; s01.x = v0; s01.y = v1;
  ulonglong2 s23; s23.x = v2; s23.y = v3;
  *(ulonglong2*)&dst[i0] = s01;
  *(ulonglong2*)&dst[i0 + 2] = s23;
}

// K2: 3 blocks/image: serially merge 7 runs -> top-1024 (r19-validated).
__global__ __launch_bounds__(256) void k_merge7(const u64* __restrict__ keyG,
                                                u64* __restrict__ midG) {
  const int b = blockIdx.x / 3;
  const int p3 = blockIdx.x % 3;
  const int t = threadIdx.x;
  const int l = t & 63;
  const int w = t >> 6;
  const int i0 = w * 256 + l * 4;
  __shared__ u64 ks[KTOP];
  const u64* src = keyG + ((size_t)b * NCH + p3 * 7) * KTOP;
  u64 v0 = src[i0 + 0], v1 = src[i0 + 1], v2 = src[i0 + 2], v3 = src[i0 + 3];
  for (int c = 1; c < 7; c++) {
    // B[i] = run[1023-i] (ascending); item i0+s at src[c*K + 1023-i0-s]
    const u64* sb = src + (size_t)c * KTOP + (KTOP - 4) - i0;
    u64 b3 = sb[0], b2 = sb[1], b1 = sb[2], b0 = sb[3];
    if (b0 > v0) v0 = b0;              // half-cleaner
    if (b1 > v1) v1 = b1;
    if (b2 > v2) v2 = b2;
    if (b3 > v3) v3 = b3;
    bm_lds(ks, v0, v1, v2, v3, l, w, 2, true);   // j=512
    bm_lds(ks, v0, v1, v2, v3, l, w, 1, true);   // j=256
    bm_low(v0, v1, v2, v3, l, true, 128);        // j=128..1
  }
  u64* d = midG + ((size_t)b * 3 + p3) * KTOP;
  ulonglong2 s01; s01.x = v0; s01.y = v1;
  ulonglong2 s23; s23.x = v2; s23.y = v3;
  *(ulonglong2*)&d[i0] = s01;
  *(ulonglong2*)&d[i0 + 2] = s23;
}

// K3: per image: merge 3 mids (register form) -> top-1024 in LDS, then the
// validated decode + valid-ballot loop (r19-validated).
__global__ __launch_bounds__(256) void k_merge3(const u64* __restrict__ midG,
                                                const float* __restrict__ locs,
                                                const float* __restrict__ priors,
                                                float* __restrict__ boxF,
                                                float* __restrict__ scoreF,
                                                u64* __restrict__ validW) {
  const int b = blockIdx.x;
  const int t = threadIdx.x;
  const int l = t & 63;
  const int w = t >> 6;
  const int i0 = w * 256 + l * 4;
  __shared__ u64 ks[KTOP];
  const u64* src = midG + (size_t)b * 3 * KTOP;
  u64 v0 = src[i0 + 0], v1 = src[i0 + 1], v2 = src[i0 + 2], v3 = src[i0 + 3];
  for (int c = 1; c < 3; c++) {
    const u64* sb = src + (size_t)c * KTOP + (KTOP - 4) - i0;
    u64 b3 = sb[0], b2 = sb[1], b1 = sb[2], b0 = sb[3];
    if (b0 > v0) v0 = b0;
    if (b1 > v1) v1 = b1;
    if (b2 > v2) v2 = b2;
    if (b3 > v3) v3 = b3;
    bm_lds(ks, v0, v1, v2, v3, l, w, 2, true);
    bm_lds(ks, v0, v1, v2, v3, l, w, 1, true);
    bm_low(v0, v1, v2, v3, l, true, 128);
  }
  ks[i0 + 0] = v0; ks[i0 + 1] = v1; ks[i0 + 2] = v2; ks[i0 + 3] = v3;
  __syncthreads();
  // decode top-1024: f32-stepwise (identical expressions to validated round 7)
  for (int i = t; i < KTOP; i += 256) {
    u64 K = ks[i];
    float sv = __uint_as_float((u32)(K >> 15));
    int idx = NPRI - 1 - (int)(K & 0x7FFFu);
    float4 lo = ((const float4*)locs)[(size_t)b * NPRI + idx];
    float4 pr = ((const float4*)priors)[idx];
    float cx = pr.x + (lo.x * 0.1f) * pr.z;
    float cy = pr.y + (lo.y * 0.1f) * pr.w;
    float wd = pr.z * crexpf(lo.z * 0.2f);
    float ht = pr.w * crexpf(lo.w * 0.2f);
    float x1 = cx - wd * 0.5f;
    float y1 = cy - ht * 0.5f;
    float x2 = x1 + wd;
    float y2 = y1 + ht;
    size_t o = (size_t)b * KTOP + i;
    boxF[o * 4 + 0] = x1;
    boxF[o * 4 + 1] = y1;
    boxF[o * 4 + 2] = x2;
    boxF[o * 4 + 3] = y2;
    scoreF[o] = sv;
    u64 mask = __ballot(sv > 0.5f);       // wave covers group i>>6
    if ((t & 63) == 0) validW[(size_t)b * 16 + (i >> 6)] = mask;
  }
}

// K4: upper-triangle suppression bitmask (r13/r17-validated IoU bits), now
// stored to the PADDED odd-stride layout (only the store index changed).
__global__ __launch_bounds__(256) void k_iou(const float* __restrict__ boxF,
                                             u64* __restrict__ supP) {
  const int bid = blockIdx.x;
  const int x8 = bid & 7;
  const int q = bid >> 3;
  const int bslot = q / 40;
  int task = q - bslot * 40;           // 0..39
  const int b = bslot * 8 + x8;        // image
  int g = 0, base = 0;
  for (int gg = 0; gg < 16; gg++) {
    int cg = (16 - gg + 3) >> 2;
    if (task < base + cg) { g = gg; break; }
    base += cg;
  }
  const int c = task - base;
  const int w0 = g + 4 * c;            // first word of this chunk
  __shared__ float4 BXS[256];
  __shared__ float ARS[256];
  const float4* bb = (const float4*)(boxF + (size_t)b * KTOP * 4);
  {
    int j = w0 * 64 + threadIdx.x;
    if (j < KTOP) {
      float4 v = bb[j];
      BXS[threadIdx.x] = v;
      ARS[threadIdx.x] = fmaxf(v.z - v.x, 0.0f) * fmaxf(v.w - v.y, 0.0f);
    }
  }
  const int r = threadIdx.x & 63;
  const int v = threadIdx.x >> 6;      // wave 0..3
  const int i = g * 64 + r;
  float4 bi = bb[i];
  float a = fmaxf(bi.z - bi.x, 0.0f) * fmaxf(bi.w - bi.y, 0.0f);
  __syncthreads();
  const int w = w0 + v;
  if (w < 16) {
    u64 word = 0;
    const int lbase = v * 64;
    for (int jb = 0; jb < 64; jb++) {
      int lj = lbase + jb;
      float4 bj = BXS[lj];             // broadcast (w uniform in wave)
      float aj = ARS[lj];
      float lx = fmaxf(bi.x, bj.x);
      float ly = fmaxf(bi.y, bj.y);
      float rx = fminf(bi.z, bj.z);
      float ry = fminf(bi.w, bj.w);
      float iw = fmaxf(rx - lx, 0.0f);
      float ih = fmaxf(ry - ly, 0.0f);
      float inter = iw * ih;
      float uni = (a + aj) - inter;
      float iou = inter / fmaxf(uni, 1e-9f);
      if (iou > 0.4f) word |= (1ULL << jb);
    }
    if (w == g) word &= (r == 63) ? 0ULL : (~0ULL << (r + 1));   // j > i
    supP[(size_t)b * SUPW + supBaseP(g) + (size_t)r * supStride(g) + (w - g)] = word;
  }
}

// K5: greedy scan v9 — frontier-fixpoint NMS on the PADDED layout:
// odd row strides make every team-sweep ds_read_b64 bank-conflict-free
// (v8's 128 B strides put all 16 team lanes on one bank pair -> ~4x over
// floor -> ~20 us). Also: wave-uniform group bound (wave wv owns words
// 4wv..4wv+3, loop g<=4wv+3) cuts sweep traffic 128->80 KB, no divergence.
// Identical OR-reduction bits to the r20-validated fixpoint.
__global__ __launch_bounds__(256) void k_scan(const u64* __restrict__ supP,
                                              const u64* __restrict__ validW,
                                              const float* __restrict__ boxF,
                                              const float* __restrict__ scoreF,
                                              float* __restrict__ out) {
  extern __shared__ u64 rows[];        // SUPW u64 = 73728 B
  const int b = blockIdx.x;
  const int t = threadIdx.x;
  const int lane = t & 63;
  const int wv = t >> 6;               // wave 0..3
  __shared__ u64 aliveA[16], aliveB[16], supW[16], keepW[16];
  __shared__ int contF[2];
  const u64* supB = supP + (size_t)b * SUPW;
  // async bulk stage: 72 chunks x 1 KB
  {
    const unsigned char* gb = (const unsigned char*)supB;
    unsigned char* lb = (unsigned char*)rows;
    for (int c = wv; c < 72; c += 4) {
      int off = c << 10;
      __builtin_amdgcn_global_load_lds(
          (const __attribute__((address_space(1))) unsigned int*)(gb + off + lane * 16),
          (__attribute__((address_space(3))) unsigned int*)(lb + off),
          16, 0, 0);
    }
  }
  if (t < 16) { aliveA[t] = validW[(size_t)b * 16 + t]; keepW[t] = 0; }
  if (t == 0) contF[0] = 0;
  __syncthreads();                     // drains vmcnt; init visible

  u64* cur = aliveA;
  u64* nxt = aliveB;
  const int w = t >> 4;                // owned suppression word 0..15
  const int k = t & 15;                // lane within word-team
  const int gmax = (wv << 2) + 3;      // wave-uniform: max w in this wave
  for (int round = 0;; ++round) {
    const int p = round & 1;
    // region 1: supW[w] = OR over alive rows i (g(i) <= w) of their word w
    u64 acc = 0;
    for (int g = 0; g <= gmax; ++g) {
      const bool act = (g <= w);
      const int s = supStride(g);
      const int base = supBaseP(g) + (w - g);   // inactive lanes: in-bounds garbage, masked
      const u64 am = cur[g];
#pragma unroll
      for (int mi = 0; mi < 4; ++mi) {
        const int r = k + 16 * mi;
        u64 rowv = rows[base + r * s];          // unconditional, conflict-free
        u64 msk = (act && ((am >> r) & 1)) ? ~0ULL : 0ULL;
        acc |= rowv & msk;
      }
    }
    acc |= shflx64(acc, 1);
    acc |= shflx64(acc, 2);
    acc |= shflx64(acc, 4);
    acc |= shflx64(acc, 8);
    if (k == 0) supW[w] = acc;
    __syncthreads();                   // A: supW stable
    // region 2: removed-by-frontier sweep + state update (writes go to nxt)
    u64 acc2 = 0;
    for (int g = 0; g <= gmax; ++g) {
      const bool act = (g <= w);
      const int s = supStride(g);
      const int base = supBaseP(g) + (w - g);
      const u64 fm = cur[g] & ~supW[g];         // frontier bits of group g
#pragma unroll
      for (int mi = 0; mi < 4; ++mi) {
        const int r = k + 16 * mi;
        u64 rowv = rows[base + r * s];
        u64 msk = (act && ((fm >> r) & 1)) ? ~0ULL : 0ULL;
        acc2 |= rowv & msk;
      }
    }
    acc2 |= shflx64(acc2, 1);
    acc2 |= shflx64(acc2, 2);
    acc2 |= shflx64(acc2, 4);
    acc2 |= shflx64(acc2, 8);
    if (k == 0) {
      u64 a = cur[w];
      u64 f = a & ~supW[w];
      keepW[w] |= f;
      u64 na = a & ~(f | acc2);
      nxt[w] = na;
      if (na) contF[p] = 1;            // benign same-value race
    }
    if (t == 0) contF[p ^ 1] = 0;      // pre-zero next round's flag
    __syncthreads();                   // B: keepW/nxt/contF stable
    if (!contF[p]) break;              // uniform: all threads read same value
    u64* tmp = cur; cur = nxt; nxt = tmp;
  }
  const float* bb = boxF + (size_t)b * KTOP * 4;
  const float* sc = scoreF + (size_t)b * KTOP;
  const float4* bb4 = (const float4*)bb;
  for (int i = t; i < KTOP; i += 256) {
    float kf = ((keepW[i >> 6] >> (i & 63)) & 1ULL) ? 1.0f : 0.0f;
    float4 bv = bb4[i];
    size_t o5 = ((size_t)b * KTOP + i) * 5;
    out[o5 + 0] = bv.x * kf;
    out[o5 + 1] = bv.y * kf;
    out[o5 + 2] = bv.z * kf;
    out[o5 + 3] = bv.w * kf;
    out[o5 + 4] = sc[i] * kf;
    out[(size_t)BATCH * KTOP * 5 + (size_t)b * KTOP + i] = kf;
  }
}

extern "C" void kernel_launch(void* const* d_in, const int* in_sizes, int n_in,
                              void* d_out, int out_size, void* d_ws, size_t ws_size,
                              hipStream_t stream) {
  const float* locs = nullptr;
  const float* confs = nullptr;
  const float* priors = nullptr;
  for (int i = 0; i < n_in; i++) {
    if (in_sizes[i] == BATCH * NPRI * 4) locs = (const float*)d_in[i];
    else if (in_sizes[i] == BATCH * NPRI * 2) confs = (const float*)d_in[i];
    else if (in_sizes[i] == NPRI * 4) priors = (const float*)d_in[i];
  }
  float* out = (float*)d_out;   // f32: [B,K,5] dets ++ [B,K] keep

  char* ws = (char*)d_ws;
  size_t off = 0;
  u64* keyG = (u64*)(ws + off);          // B*21*1024*8 = 11,010,048
  u64* supP = (u64*)(ws + off);          // alias: keyG dead after k_merge7 (64*9216*8 = 4,718,592)
  off += (size_t)BATCH * NCH * KTOP * 8;
  u64* midG = (u64*)(ws + off);          off += (size_t)BATCH * 3 * KTOP * 8;   // 1,572,864
  float* boxF = (float*)(ws + off);      off += (size_t)BATCH * KTOP * 4 * 4;   // 1,048,576
  float* scoreF = (float*)(ws + off);    off += (size_t)BATCH * KTOP * 4;       //   262,144
  u64* validW = (u64*)(ws + off);        off += (size_t)BATCH * 16 * 8;         //     8,192
  // total ~13.9 MB

  k_sort<<<BATCH * NCH, 256, 0, stream>>>(confs, keyG);
  k_merge7<<<BATCH * 3, 256, 0, stream>>>(keyG, midG);
  k_merge3<<<BATCH, 256, 0, stream>>>(midG, locs, priors, boxF, scoreF, validW);
  k_iou<<<2560, 256, 0, stream>>>(boxF, supP);
  k_scan<<<BATCH, 256, SUPW * 8, stream>>>(supP, validW, boxF, scoreF, out);
}